// Round 3
// baseline (1651.880 us; speedup 1.0000x reference)
//
#include <hip/hip_runtime.h>

#define H 128

typedef __attribute__((ext_vector_type(8))) short short8v;   // 8 bf16 (4 VGPRs)
typedef __attribute__((ext_vector_type(4))) float f32x4;

// ---------------- bf16 split helpers ----------------

__device__ inline unsigned short bfr(float x) {
  unsigned u = __float_as_uint(x);
  return (unsigned short)((u + 0x8000u) >> 16);   // round-half-up to bf16
}
__device__ inline float ubf(unsigned short h) {
  return __uint_as_float(((unsigned)h) << 16);
}
__device__ inline void bsplit(float x, unsigned short& h, unsigned short& l) {
  h = bfr(x);
  l = bfr(x - ubf(h));   // residual
}

// ---------------- histograms ----------------

__global__ void hist_kernel(const int* __restrict__ ids, int* __restrict__ cnt, int n) {
  int i = blockIdx.x * blockDim.x + threadIdx.x;
  if (i < n) atomicAdd(&cnt[ids[i]], 1);
}

// one read of dst feeds both the per-node degree and the per-bin count
__global__ void hist_deg_bin_kernel(const int* __restrict__ dst, int* __restrict__ deg,
                                    int* __restrict__ bcnt, int n) {
  int i = blockIdx.x * blockDim.x + threadIdx.x;
  if (i < n) {
    int d = dst[i];
    atomicAdd(&deg[d], 1);
    atomicAdd(&bcnt[d >> 7], 1);
  }
}

// ---------------- binned CSR fill (two-pass, write-amplification-free) ----------------
// pass1: scatter packed (dst_local<<17 | src) into per-bin regions (bins hot in L2)
__global__ void pass1_bin_kernel(const int* __restrict__ src, const int* __restrict__ dst,
                                 int* __restrict__ bcur, unsigned* __restrict__ ebuf, int n) {
  int i = blockIdx.x * blockDim.x + threadIdx.x;
  if (i < n) {
    int d = dst[i];
    int p = atomicAdd(&bcur[d >> 7], 1);
    ebuf[p] = (unsigned)src[i] | ((unsigned)(d & 127) << 17);
  }
}

// pass2: one block per bin; adj window per bin ~12KB -> L2-resident writes
__global__ __launch_bounds__(256) void pass2_fill_kernel(const unsigned* __restrict__ ebuf,
                                                         const int* __restrict__ bptr,
                                                         int* __restrict__ cursor,
                                                         int* __restrict__ adj) {
  int b = blockIdx.x;
  int beg = bptr[b], end = bptr[b + 1];
  int base = b << 7;
  for (int j = beg + (int)threadIdx.x; j < end; j += 256) {
    unsigned e = ebuf[j];
    int s = (int)(e & 0x1FFFFu);
    int d = base + (int)(e >> 17);
    int p = atomicAdd(&cursor[d], 1);
    adj[p] = s;
  }
}

// ---- hierarchical scan: scan1 (per-block excl) -> scan2 (block sums) -> scan3 (add) ----

__global__ __launch_bounds__(1024) void scan1_kernel(const int* __restrict__ in,
                                                     int* __restrict__ out,
                                                     int* __restrict__ bsum, int n) {
  __shared__ int wsum[16];
  int t = threadIdx.x;
  int i = blockIdx.x * 1024 + t;
  int lane = t & 63, w = t >> 6;
  int v = (i < n) ? in[i] : 0;
  int acc = v;
  #pragma unroll
  for (int off = 1; off < 64; off <<= 1) {
    int g = __shfl_up(acc, off, 64);
    if (lane >= off) acc += g;
  }
  if (lane == 63) wsum[w] = acc;
  __syncthreads();
  int woff = 0;
  for (int j = 0; j < w; ++j) woff += wsum[j];
  if (i < n) out[i] = woff + acc - v;
  if (t == 1023) bsum[blockIdx.x] = woff + acc;
}

__global__ __launch_bounds__(256) void scan2_kernel(int* __restrict__ bsum, int nb) {
  __shared__ int s[256];
  int t = threadIdx.x;
  s[t] = (t < nb) ? bsum[t] : 0;
  __syncthreads();
  #pragma unroll
  for (int off = 1; off < 256; off <<= 1) {
    int v = (t >= off) ? s[t - off] : 0;
    __syncthreads();
    s[t] += v;
    __syncthreads();
  }
  if (t < nb) bsum[t] = (t == 0) ? 0 : s[t - 1];
}

__global__ __launch_bounds__(1024) void scan3_kernel(const int* __restrict__ bsum,
                                                     const int* __restrict__ deg,
                                                     int* __restrict__ rp,
                                                     int* __restrict__ cur, int n) {
  int i = blockIdx.x * 1024 + threadIdx.x;
  if (i < n) {
    int v = rp[i] + bsum[blockIdx.x];
    rp[i] = v;
    cur[i] = v;
    if (i == n - 1) rp[n] = v + deg[i];
  }
}

// small single-block scan (n<=1024): writes out[0..n], optional second copy
__global__ __launch_bounds__(1024) void scan_small_kernel(const int* __restrict__ in,
                                                          int* __restrict__ out,
                                                          int* __restrict__ out2, int n) {
  __shared__ int wsum[16];
  int t = threadIdx.x;
  int lane = t & 63, w = t >> 6;
  int v = (t < n) ? in[t] : 0;
  int acc = v;
  #pragma unroll
  for (int off = 1; off < 64; off <<= 1) {
    int g = __shfl_up(acc, off, 64);
    if (lane >= off) acc += g;
  }
  if (lane == 63) wsum[w] = acc;
  __syncthreads();
  int woff = 0;
  for (int j = 0; j < w; ++j) woff += wsum[j];
  if (t < n) {
    int e = woff + acc - v;
    out[t] = e;
    if (out2) out2[t] = e;
  }
  if (t == n - 1) {
    out[n] = woff + acc;
    if (out2) out2[n] = woff + acc;
  }
}

// ---------------- GIN aggregate: z[v] = (1+eps)*h[v] + sum_{u in N_in(v)} h[u] ----------------

__global__ __launch_bounds__(256) void aggregate_kernel(
    const float* __restrict__ h, float* __restrict__ z,
    const int* __restrict__ row_ptr, const int* __restrict__ adj,
    const float* __restrict__ eps, int layer, int n)
{
  int wid = (blockIdx.x * 256 + threadIdx.x) >> 6;   // one wave per node
  int lane = threadIdx.x & 63;
  if (wid >= n) return;
  float e = 1.0f + eps[layer];
  int beg = row_ptr[wid], end = row_ptr[wid + 1];
  const float2* hv = (const float2*)h;
  float2 a = hv[(size_t)wid * 64 + lane];
  float sx = a.x * e, sy = a.y * e;
  int p = beg;
  // 8 independent row loads in flight (memory-level parallelism)
  for (; p + 8 <= end; p += 8) {
    int u0 = adj[p], u1 = adj[p + 1], u2 = adj[p + 2], u3 = adj[p + 3];
    int u4 = adj[p + 4], u5 = adj[p + 5], u6 = adj[p + 6], u7 = adj[p + 7];
    float2 b0 = hv[(size_t)u0 * 64 + lane];
    float2 b1 = hv[(size_t)u1 * 64 + lane];
    float2 b2 = hv[(size_t)u2 * 64 + lane];
    float2 b3 = hv[(size_t)u3 * 64 + lane];
    float2 b4 = hv[(size_t)u4 * 64 + lane];
    float2 b5 = hv[(size_t)u5 * 64 + lane];
    float2 b6 = hv[(size_t)u6 * 64 + lane];
    float2 b7 = hv[(size_t)u7 * 64 + lane];
    sx += ((b0.x + b1.x) + (b2.x + b3.x)) + ((b4.x + b5.x) + (b6.x + b7.x));
    sy += ((b0.y + b1.y) + (b2.y + b3.y)) + ((b4.y + b5.y) + (b6.y + b7.y));
  }
  for (; p + 2 <= end; p += 2) {
    int u0 = adj[p], u1 = adj[p + 1];
    float2 b0 = hv[(size_t)u0 * 64 + lane];
    float2 b1 = hv[(size_t)u1 * 64 + lane];
    sx += b0.x + b1.x;
    sy += b0.y + b1.y;
  }
  if (p < end) {
    int u = adj[p];
    float2 b = hv[(size_t)u * 64 + lane];
    sx += b.x; sy += b.y;
  }
  float2 o; o.x = sx; o.y = sy;
  ((float2*)z)[(size_t)wid * 64 + lane] = o;
}

// ---------------- W prep: fp32 [k][c] -> split-bf16, transposed, swizzled planes ----------------
// Granule (col, kg): 8 contiguous k of column col at granule index
// g2 = col*16 + (kg ^ (col & 7))   (16B XOR swizzle baked into the global layout)

__global__ __launch_bounds__(256) void prep_w_kernel(
    const float* w0, const float* w1, const float* w2, const float* w3, const float* w4,
    const float* w5, const float* w6, const float* w7, const float* w8,
    unsigned short* __restrict__ Wt)
{
  int m = blockIdx.x >> 3;                 // 9 matrices x 8 blocks
  int bb = blockIdx.x & 7;
  const float* ws[9] = {w0, w1, w2, w3, w4, w5, w6, w7, w8};
  const float* W = ws[m];
  unsigned short* hi = Wt + (size_t)m * 32768;
  unsigned short* lo = hi + 16384;
  int gid = bb * 256 + threadIdx.x;        // 0..2047
  int col = gid & 127;
  int kg  = gid >> 7;                      // 0..15
  short8v vh, vl;
  #pragma unroll
  for (int j = 0; j < 8; ++j) {
    float v = W[(kg * 8 + j) * H + col];
    unsigned short h, l;
    bsplit(v, h, l);
    vh[j] = (short)h;
    vl[j] = (short)l;
  }
  int g2 = col * 16 + (kg ^ (col & 7));
  *(short8v*)(hi + (size_t)g2 * 8) = vh;
  *(short8v*)(lo + (size_t)g2 * 8) = vl;
}

// ---------------- shared fragment helpers ----------------

// B-fragment (hi,lo) for column-block n, k-chunk kg, lane row lr, from a W plane base
__device__ inline void load_wfrag(const unsigned short* __restrict__ Wp,
                                  int n, int lr, int kg, short8v& wh, short8v& wl) {
  int col = n * 16 + lr;
  int g2 = col * 16 + (kg ^ (col & 7));
  wh = *(const short8v*)(Wp + (size_t)g2 * 8);
  wl = *(const short8v*)(Wp + 16384 + (size_t)g2 * 8);
}

// ---------------- plain MFMA GEMM (encoder + head) ----------------

__global__ __launch_bounds__(256, 2) void gemm_mfma_kernel(
    const float* __restrict__ A, const unsigned short* __restrict__ Wt,
    float* __restrict__ out,
    const float* __restrict__ bias, const float* __restrict__ gw,
    const float* __restrict__ bb_, const float* __restrict__ bm,
    const float* __restrict__ bv, int relu, int nrows)
{
  __shared__ float4 ldsv[4096];            // 64 KB hi+lo planes
  unsigned short* lds = (unsigned short*)ldsv;
  int t = threadIdx.x;
  {
    const float4* srcv = (const float4*)Wt;
    #pragma unroll
    for (int i = 0; i < 16; ++i) ldsv[t + 256 * i] = srcv[t + 256 * i];
  }
  __syncthreads();

  int w = t >> 6, l = t & 63;
  int lr = l & 15, lk = l >> 4;
  int row0 = blockIdx.x * 128 + w * 32;

  f32x4 acc[2][8];
  #pragma unroll
  for (int m = 0; m < 2; ++m)
    #pragma unroll
    for (int n = 0; n < 8; ++n) acc[m][n] = (f32x4){0.f, 0.f, 0.f, 0.f};

  const float* Ap[2];
  #pragma unroll
  for (int m = 0; m < 2; ++m) {
    int r = row0 + m * 16 + lr;
    if (r > nrows - 1) r = nrows - 1;
    Ap[m] = A + (size_t)r * H + lk * 8;
  }

  #pragma unroll
  for (int k4 = 0; k4 < 4; ++k4) {
    short8v ah[2], al[2];
    #pragma unroll
    for (int m = 0; m < 2; ++m) {
      f32x4 a0 = *(const f32x4*)(Ap[m] + k4 * 32);
      f32x4 a1 = *(const f32x4*)(Ap[m] + k4 * 32 + 4);
      #pragma unroll
      for (int j = 0; j < 4; ++j) {
        unsigned short hh, ll;
        bsplit(a0[j], hh, ll); ah[m][j] = (short)hh; al[m][j] = (short)ll;
        bsplit(a1[j], hh, ll); ah[m][4 + j] = (short)hh; al[m][4 + j] = (short)ll;
      }
    }
    int kg = k4 * 4 + lk;
    #pragma unroll
    for (int n = 0; n < 8; ++n) {
      int col = n * 16 + lr;
      int g2 = col * 16 + (kg ^ (col & 7));
      short8v wh = *(const short8v*)(lds + (size_t)g2 * 8);
      short8v wl = *(const short8v*)(lds + 16384 + (size_t)g2 * 8);
      acc[0][n] = __builtin_amdgcn_mfma_f32_16x16x32_bf16(ah[0], wh, acc[0][n], 0, 0, 0);
      acc[1][n] = __builtin_amdgcn_mfma_f32_16x16x32_bf16(ah[1], wh, acc[1][n], 0, 0, 0);
      acc[0][n] = __builtin_amdgcn_mfma_f32_16x16x32_bf16(al[0], wh, acc[0][n], 0, 0, 0);
      acc[1][n] = __builtin_amdgcn_mfma_f32_16x16x32_bf16(al[1], wh, acc[1][n], 0, 0, 0);
      acc[0][n] = __builtin_amdgcn_mfma_f32_16x16x32_bf16(ah[0], wl, acc[0][n], 0, 0, 0);
      acc[1][n] = __builtin_amdgcn_mfma_f32_16x16x32_bf16(ah[1], wl, acc[1][n], 0, 0, 0);
      acc[0][n] = __builtin_amdgcn_mfma_f32_16x16x32_bf16(al[0], wl, acc[0][n], 0, 0, 0);
      acc[1][n] = __builtin_amdgcn_mfma_f32_16x16x32_bf16(al[1], wl, acc[1][n], 0, 0, 0);
    }
  }
  __syncthreads();

  #pragma unroll
  for (int n = 0; n < 8; ++n) {
    int c = n * 16 + lr;
    float sc = bv ? rsqrtf(bv[c] + 1e-5f) : 1.0f;
    float gg = gw ? gw[c] : 1.0f;
    float S = gg * sc;
    float T = ((bias ? bias[c] : 0.0f) - (bm ? bm[c] : 0.0f)) * S + (bb_ ? bb_[c] : 0.0f);
    #pragma unroll
    for (int m = 0; m < 2; ++m) {
      int rowb = row0 + m * 16 + lk * 4;
      #pragma unroll
      for (int r = 0; r < 4; ++r) {
        int row = rowb + r;
        if (row < nrows) {
          float vv = acc[m][n][r] * S + T;
          if (relu) vv = fmaxf(vv, 0.0f);
          out[(size_t)row * H + c] = vv;
        }
      }
    }
  }
}

// ---------------- fused per-layer MLP: relu(bn2( relu(bn1(Z@W1+b1)) @ W2 + b2 )) ----------------
// z1 stays on-chip: packed split-bf16 ((lo<<16)|hi) u32 in a 64KB XOR-swizzled LDS tile.
// W1/W2 fragments read straight from the pre-swizzled global planes (64KB each, L2-hot).
// LDS rows are wave-private (wave w owns rows [w*32, w*32+32)).

__device__ inline int zswz(int row, int col) {   // u32 index in zs[128*128]
  int s = (row ^ (row >> 3)) & 7;
  return row * 128 + (col ^ (s << 3));
}

__global__ __launch_bounds__(256, 2) void fused_mlp_kernel(
    const float* __restrict__ A, const unsigned short* __restrict__ W1,
    const unsigned short* __restrict__ W2, float* __restrict__ out,
    const float* __restrict__ b1, const float* __restrict__ g1,
    const float* __restrict__ be1, const float* __restrict__ m1, const float* __restrict__ v1,
    const float* __restrict__ b2, const float* __restrict__ g2,
    const float* __restrict__ be2, const float* __restrict__ m2, const float* __restrict__ v2,
    int nrows)
{
  __shared__ unsigned zs[128 * 128];       // 64 KB
  int t = threadIdx.x;
  int w = t >> 6, l = t & 63;
  int lr = l & 15, lk = l >> 4;
  int row0 = blockIdx.x * 128 + w * 32;

  f32x4 acc[2][8];
  #pragma unroll
  for (int m = 0; m < 2; ++m)
    #pragma unroll
    for (int n = 0; n < 8; ++n) acc[m][n] = (f32x4){0.f, 0.f, 0.f, 0.f};

  const float* Ap[2];
  #pragma unroll
  for (int m = 0; m < 2; ++m) {
    int r = row0 + m * 16 + lr;
    if (r > nrows - 1) r = nrows - 1;
    Ap[m] = A + (size_t)r * H + lk * 8;
  }

  // ---- GEMM1: acc = A @ W1 ----
  #pragma unroll
  for (int k4 = 0; k4 < 4; ++k4) {
    short8v ah[2], al[2];
    #pragma unroll
    for (int m = 0; m < 2; ++m) {
      f32x4 a0 = *(const f32x4*)(Ap[m] + k4 * 32);
      f32x4 a1 = *(const f32x4*)(Ap[m] + k4 * 32 + 4);
      #pragma unroll
      for (int j = 0; j < 4; ++j) {
        unsigned short hh, ll;
        bsplit(a0[j], hh, ll); ah[m][j] = (short)hh; al[m][j] = (short)ll;
        bsplit(a1[j], hh, ll); ah[m][4 + j] = (short)hh; al[m][4 + j] = (short)ll;
      }
    }
    int kg = k4 * 4 + lk;
    #pragma unroll
    for (int n = 0; n < 8; ++n) {
      short8v wh, wl;
      load_wfrag(W1, n, lr, kg, wh, wl);
      acc[0][n] = __builtin_amdgcn_mfma_f32_16x16x32_bf16(ah[0], wh, acc[0][n], 0, 0, 0);
      acc[1][n] = __builtin_amdgcn_mfma_f32_16x16x32_bf16(ah[1], wh, acc[1][n], 0, 0, 0);
      acc[0][n] = __builtin_amdgcn_mfma_f32_16x16x32_bf16(al[0], wh, acc[0][n], 0, 0, 0);
      acc[1][n] = __builtin_amdgcn_mfma_f32_16x16x32_bf16(al[1], wh, acc[1][n], 0, 0, 0);
      acc[0][n] = __builtin_amdgcn_mfma_f32_16x16x32_bf16(ah[0], wl, acc[0][n], 0, 0, 0);
      acc[1][n] = __builtin_amdgcn_mfma_f32_16x16x32_bf16(ah[1], wl, acc[1][n], 0, 0, 0);
      acc[0][n] = __builtin_amdgcn_mfma_f32_16x16x32_bf16(al[0], wl, acc[0][n], 0, 0, 0);
      acc[1][n] = __builtin_amdgcn_mfma_f32_16x16x32_bf16(al[1], wl, acc[1][n], 0, 0, 0);
    }
  }

  // ---- epilogue1 + pack to LDS (rows are wave-private) ----
  #pragma unroll
  for (int n = 0; n < 8; ++n) {
    int c = n * 16 + lr;
    float S = g1[c] * rsqrtf(v1[c] + 1e-5f);
    float T = (b1[c] - m1[c]) * S + be1[c];
    #pragma unroll
    for (int m = 0; m < 2; ++m) {
      int rowb = w * 32 + m * 16 + lk * 4;   // block-local row
      #pragma unroll
      for (int r = 0; r < 4; ++r) {
        float vv = fmaxf(acc[m][n][r] * S + T, 0.0f);
        unsigned short hh, ll;
        bsplit(vv, hh, ll);
        zs[zswz(rowb + r, c)] = (unsigned)hh | ((unsigned)ll << 16);
      }
    }
  }
  __syncthreads();

  // ---- GEMM2: acc = z1 @ W2 ----
  #pragma unroll
  for (int m = 0; m < 2; ++m)
    #pragma unroll
    for (int n = 0; n < 8; ++n) acc[m][n] = (f32x4){0.f, 0.f, 0.f, 0.f};

  #pragma unroll
  for (int k4 = 0; k4 < 4; ++k4) {
    short8v ah[2], al[2];
    #pragma unroll
    for (int m = 0; m < 2; ++m) {
      int rowl = w * 32 + m * 16 + lr;
      int s = (rowl ^ (rowl >> 3)) & 7;
      int base8 = (k4 * 4 + lk) ^ s;                 // 8-col granule after swizzle
      const unsigned* zp = &zs[rowl * 128 + base8 * 8];
      unsigned u0 = zp[0], u1 = zp[1], u2 = zp[2], u3 = zp[3];
      unsigned u4 = zp[4], u5 = zp[5], u6 = zp[6], u7 = zp[7];
      ah[m][0] = (short)(u0 & 0xffff); al[m][0] = (short)(u0 >> 16);
      ah[m][1] = (short)(u1 & 0xffff); al[m][1] = (short)(u1 >> 16);
      ah[m][2] = (short)(u2 & 0xffff); al[m][2] = (short)(u2 >> 16);
      ah[m][3] = (short)(u3 & 0xffff); al[m][3] = (short)(u3 >> 16);
      ah[m][4] = (short)(u4 & 0xffff); al[m][4] = (short)(u4 >> 16);
      ah[m][5] = (short)(u5 & 0xffff); al[m][5] = (short)(u5 >> 16);
      ah[m][6] = (short)(u6 & 0xffff); al[m][6] = (short)(u6 >> 16);
      ah[m][7] = (short)(u7 & 0xffff); al[m][7] = (short)(u7 >> 16);
    }
    int kg = k4 * 4 + lk;
    #pragma unroll
    for (int n = 0; n < 8; ++n) {
      short8v wh, wl;
      load_wfrag(W2, n, lr, kg, wh, wl);
      acc[0][n] = __builtin_amdgcn_mfma_f32_16x16x32_bf16(ah[0], wh, acc[0][n], 0, 0, 0);
      acc[1][n] = __builtin_amdgcn_mfma_f32_16x16x32_bf16(ah[1], wh, acc[1][n], 0, 0, 0);
      acc[0][n] = __builtin_amdgcn_mfma_f32_16x16x32_bf16(al[0], wh, acc[0][n], 0, 0, 0);
      acc[1][n] = __builtin_amdgcn_mfma_f32_16x16x32_bf16(al[1], wh, acc[1][n], 0, 0, 0);
      acc[0][n] = __builtin_amdgcn_mfma_f32_16x16x32_bf16(ah[0], wl, acc[0][n], 0, 0, 0);
      acc[1][n] = __builtin_amdgcn_mfma_f32_16x16x32_bf16(al[1], wl, acc[1][n], 0, 0, 0);   // placeholder fixed below
      acc[0][n] = __builtin_amdgcn_mfma_f32_16x16x32_bf16(al[0], wl, acc[0][n], 0, 0, 0);
      acc[1][n] = __builtin_amdgcn_mfma_f32_16x16x32_bf16(ah[1], wl, acc[1][n], 0, 0, 0);
    }
  }

  // ---- epilogue2 + store ----
  #pragma unroll
  for (int n = 0; n < 8; ++n) {
    int c = n * 16 + lr;
    float S = g2[c] * rsqrtf(v2[c] + 1e-5f);
    float T = (b2[c] - m2[c]) * S + be2[c];
    #pragma unroll
    for (int m = 0; m < 2; ++m) {
      int rowb = row0 + m * 16 + lk * 4;
      #pragma unroll
      for (int r = 0; r < 4; ++r) {
        int row = rowb + r;
        if (row < nrows) {
          out[(size_t)row * H + c] = fmaxf(acc[m][n][r] * S + T, 0.0f);
        }
      }
    }
  }
}

// ---------------- mean pool over sorted batch segments ----------------

__global__ __launch_bounds__(128) void pool_kernel(const float* __restrict__ h,
                                                   float* __restrict__ pooled,
                                                   const int* __restrict__ gptr) {
  int g = blockIdx.x, c = threadIdx.x;
  int beg = gptr[g], end = gptr[g + 1];
  float s = 0.0f;
  int i = beg;
  for (; i + 4 <= end; i += 4) {
    float a0 = h[(size_t)i * H + c];
    float a1 = h[(size_t)(i + 1) * H + c];
    float a2 = h[(size_t)(i + 2) * H + c];
    float a3 = h[(size_t)(i + 3) * H + c];
    s += (a0 + a1) + (a2 + a3);
  }
  for (; i < end; ++i) s += h[(size_t)i * H + c];
  float cnt = (float)(end - beg);
  pooled[(size_t)g * H + c] = s / fmaxf(cnt, 1.0f);
}

// ---------------- launch ----------------

extern "C" void kernel_launch(void* const* d_in, const int* in_sizes, int n_in,
                              void* d_out, int out_size, void* d_ws, size_t ws_size,
                              hipStream_t stream) {
  const float* x      = (const float*)d_in[0];
  const int*   ei     = (const int*)d_in[1];
  const int*   batch  = (const int*)d_in[2];
  const float* enc_W  = (const float*)d_in[3];
  const float* enc_b  = (const float*)d_in[4];
  const float* eps    = (const float*)d_in[5];
  const float* mlp1_W = (const float*)d_in[6];
  const float* mlp1_b = (const float*)d_in[7];
  const float* mlp1_g = (const float*)d_in[8];
  const float* mlp1_be= (const float*)d_in[9];
  const float* mlp1_m = (const float*)d_in[10];
  const float* mlp1_v = (const float*)d_in[11];
  const float* mlp2_W = (const float*)d_in[12];
  const float* mlp2_b = (const float*)d_in[13];
  const float* bn_g   = (const float*)d_in[14];
  const float* bn_b   = (const float*)d_in[15];
  const float* bn_m   = (const float*)d_in[16];
  const float* bn_v   = (const float*)d_in[17];
  const float* hW1    = (const float*)d_in[18];
  const float* hb1    = (const float*)d_in[19];
  const float* hg     = (const float*)d_in[20];
  const float* hbe    = (const float*)d_in[21];
  const float* hm     = (const float*)d_in[22];
  const float* hv     = (const float*)d_in[23];
  const float* hW2    = (const float*)d_in[24];
  const float* hb2    = (const float*)d_in[25];

  const int N = in_sizes[0] / H;   // 100000
  const int E = in_sizes[1] / 2;   // 1600000
  const int G = out_size / H;      // 512
  const int L = in_sizes[5];       // 3
  const int NB = (N + 127) >> 7;   // dst bins of 128 nodes

  const int* src = ei;
  const int* dst = ei + E;

  char* p = (char*)d_ws;
  auto alloc = [&](size_t bytes) -> char* {
    char* r = p;
    p += (bytes + 255) & ~(size_t)255;
    return r;
  };
  float* bufA   = (float*)alloc((size_t)N * H * sizeof(float));
  float* bufB   = (float*)alloc((size_t)N * H * sizeof(float));
  int*   adj    = (int*)alloc((size_t)E * sizeof(int));
  int*   deg    = (int*)alloc((size_t)N * sizeof(int));
  int*   bcnt   = (int*)alloc((size_t)NB * sizeof(int));
  int*   gcount = (int*)alloc((size_t)G * sizeof(int));
  int*   row_ptr= (int*)alloc((size_t)(N + 1) * sizeof(int));
  int*   cursor = (int*)alloc((size_t)(N + 1) * sizeof(int));
  int*   bptr   = (int*)alloc((size_t)(NB + 1) * sizeof(int));
  int*   bcur   = (int*)alloc((size_t)(NB + 1) * sizeof(int));
  int*   bsum   = (int*)alloc(256 * sizeof(int));
  int*   gptr   = (int*)alloc((size_t)(G + 1) * sizeof(int));
  float* pooled = (float*)alloc((size_t)G * H * sizeof(float));
  float* z1     = (float*)alloc((size_t)G * H * sizeof(float));
  unsigned short* Wt = (unsigned short*)alloc((size_t)9 * 32768 * sizeof(unsigned short));
  unsigned* ebuf = (unsigned*)bufA;   // alias: consumed before first GEMM writes bufA

  // zero deg..gcount in one shot (they are adjacent in the arena)
  hipMemsetAsync(deg, 0, (size_t)((char*)gcount + G * sizeof(int) - (char*)deg), stream);

  hist_deg_bin_kernel<<<(E + 255) / 256, 256, 0, stream>>>(dst, deg, bcnt, E);
  hist_kernel<<<(N + 255) / 256, 256, 0, stream>>>(batch, gcount, N);

  int nb1 = (N + 1023) / 1024;
  scan1_kernel<<<nb1, 1024, 0, stream>>>(deg, row_ptr, bsum, N);
  scan2_kernel<<<1, 256, 0, stream>>>(bsum, nb1);
  scan3_kernel<<<nb1, 1024, 0, stream>>>(bsum, deg, row_ptr, cursor, N);
  scan_small_kernel<<<1, 1024, 0, stream>>>(bcnt, bptr, bcur, NB);
  scan_small_kernel<<<1, 1024, 0, stream>>>(gcount, gptr, nullptr, G);

  pass1_bin_kernel<<<(E + 255) / 256, 256, 0, stream>>>(src, dst, bcur, ebuf, E);
  pass2_fill_kernel<<<NB, 256, 0, stream>>>(ebuf, bptr, cursor, adj);

  prep_w_kernel<<<9 * 8, 256, 0, stream>>>(
      enc_W,
      mlp1_W, mlp1_W + (size_t)H * H, mlp1_W + (size_t)2 * H * H,
      mlp2_W, mlp2_W + (size_t)H * H, mlp2_W + (size_t)2 * H * H,
      hW1, hW2, Wt);

  // node encoder: h = x @ enc_W + enc_b   (writes bufA; ebuf alias dead by now)
  gemm_mfma_kernel<<<(N + 127) / 128, 256, 0, stream>>>(
      x, Wt + 0 * 32768, bufA, enc_b, nullptr, nullptr, nullptr, nullptr, 0, N);

  float* cur = bufA;
  float* nxt = bufB;
  for (int l = 0; l < L; ++l) {
    aggregate_kernel<<<(N + 3) / 4, 256, 0, stream>>>(cur, nxt, row_ptr, adj, eps, l, N);
    fused_mlp_kernel<<<(N + 127) / 128, 256, 0, stream>>>(
        nxt, Wt + (size_t)(1 + l) * 32768, Wt + (size_t)(4 + l) * 32768, nxt,
        mlp1_b + l * H, mlp1_g + l * H, mlp1_be + l * H, mlp1_m + l * H, mlp1_v + l * H,
        mlp2_b + l * H, bn_g + l * H, bn_b + l * H, bn_m + l * H, bn_v + l * H, N);
    float* tmp = cur; cur = nxt; nxt = tmp;
  }

  pool_kernel<<<G, 128, 0, stream>>>(cur, pooled, gptr);

  gemm_mfma_kernel<<<(G + 127) / 128, 256, 0, stream>>>(
      pooled, Wt + (size_t)7 * 32768, z1, hb1, hg, hbe, hm, hv, 1, G);
  gemm_mfma_kernel<<<(G + 127) / 128, 256, 0, stream>>>(
      z1, Wt + (size_t)8 * 32768, (float*)d_out, hb2, nullptr, nullptr, nullptr, nullptr, 0, G);
}

// Round 4
// 891.968 us; speedup vs baseline: 1.8520x; 1.8520x over previous
//
#include <hip/hip_runtime.h>

#define H 128

typedef __attribute__((ext_vector_type(8))) short short8v;   // 8 bf16 (4 VGPRs)
typedef __attribute__((ext_vector_type(4))) float f32x4;

// ---------------- bf16 split helpers ----------------

__device__ inline unsigned short bfr(float x) {
  unsigned u = __float_as_uint(x);
  return (unsigned short)((u + 0x8000u) >> 16);   // round-half-up to bf16
}
__device__ inline float ubf(unsigned short h) {
  return __uint_as_float(((unsigned)h) << 16);
}
__device__ inline void bsplit(float x, unsigned short& h, unsigned short& l) {
  h = bfr(x);
  l = bfr(x - ubf(h));   // residual
}

// ---------------- degree histogram (100K addresses, ~16 collisions/addr: OK) ----------------

__global__ void hist_kernel(const int* __restrict__ ids, int* __restrict__ cnt, int n) {
  int i = blockIdx.x * blockDim.x + threadIdx.x;
  if (i < n) atomicAdd(&cnt[ids[i]], 1);
}

// ---------------- gptr from sorted batch: no atomics at all ----------------

__global__ void gptr_kernel(const int* __restrict__ batch, int* __restrict__ gptr,
                            int n, int G) {
  int i = blockIdx.x * blockDim.x + threadIdx.x;
  if (i >= n) return;
  int b = batch[i];
  int pb = (i == 0) ? -1 : batch[i - 1];
  for (int g = pb + 1; g <= b; ++g) gptr[g] = i;   // few iters total across grid
  if (i == n - 1)
    for (int g = b + 1; g <= G; ++g) gptr[g] = n;
}

// ---- hierarchical scan: scan1 (per-block excl) -> scan2 (block sums) -> scan3 (add) ----

__global__ __launch_bounds__(1024) void scan1_kernel(const int* __restrict__ in,
                                                     int* __restrict__ out,
                                                     int* __restrict__ bsum, int n) {
  __shared__ int wsum[16];
  int t = threadIdx.x;
  int i = blockIdx.x * 1024 + t;
  int lane = t & 63, w = t >> 6;
  int v = (i < n) ? in[i] : 0;
  int acc = v;
  #pragma unroll
  for (int off = 1; off < 64; off <<= 1) {
    int g = __shfl_up(acc, off, 64);
    if (lane >= off) acc += g;
  }
  if (lane == 63) wsum[w] = acc;
  __syncthreads();
  int woff = 0;
  for (int j = 0; j < w; ++j) woff += wsum[j];
  if (i < n) out[i] = woff + acc - v;
  if (t == 1023) bsum[blockIdx.x] = woff + acc;
}

__global__ __launch_bounds__(256) void scan2_kernel(int* __restrict__ bsum, int nb) {
  __shared__ int s[256];
  int t = threadIdx.x;
  s[t] = (t < nb) ? bsum[t] : 0;
  __syncthreads();
  #pragma unroll
  for (int off = 1; off < 256; off <<= 1) {
    int v = (t >= off) ? s[t - off] : 0;
    __syncthreads();
    s[t] += v;
    __syncthreads();
  }
  if (t < nb) bsum[t] = (t == 0) ? 0 : s[t - 1];
}

__global__ __launch_bounds__(1024) void scan3_kernel(const int* __restrict__ bsum,
                                                     const int* __restrict__ deg,
                                                     int* __restrict__ rp,
                                                     int* __restrict__ cur, int n) {
  int i = blockIdx.x * 1024 + threadIdx.x;
  if (i < n) {
    int v = rp[i] + bsum[blockIdx.x];
    rp[i] = v;
    cur[i] = v;
    if (i == n - 1) rp[n] = v + deg[i];
  }
}

// ---------------- ranged CSR fill ----------------
// Pass k handles dst in [lo,hi): active adj window ~E/8*4B = 800KB and cursor
// region ~50KB stay L2-resident -> scattered 4B writes fill lines in L2 before
// eviction (no HBM write amplification); cursor atomics stay at ~16 collisions.

__global__ void fill_adj_ranged_kernel(const int* __restrict__ src,
                                       const int* __restrict__ dst,
                                       int* __restrict__ cursor, int* __restrict__ adj,
                                       int n, int lo, int hi) {
  int i = blockIdx.x * blockDim.x + threadIdx.x;
  if (i < n) {
    int d = dst[i];
    if (d >= lo && d < hi) {
      int p = atomicAdd(&cursor[d], 1);
      adj[p] = src[i];
    }
  }
}

// ---------------- GIN aggregate: z[v] = (1+eps)*h[v] + sum_{u in N_in(v)} h[u] ----------------

__global__ __launch_bounds__(256) void aggregate_kernel(
    const float* __restrict__ h, float* __restrict__ z,
    const int* __restrict__ row_ptr, const int* __restrict__ adj,
    const float* __restrict__ eps, int layer, int n)
{
  int wid = (blockIdx.x * 256 + threadIdx.x) >> 6;   // one wave per node
  int lane = threadIdx.x & 63;
  if (wid >= n) return;
  float e = 1.0f + eps[layer];
  int beg = row_ptr[wid], end = row_ptr[wid + 1];
  const float2* hv = (const float2*)h;
  float2 a = hv[(size_t)wid * 64 + lane];
  float sx = a.x * e, sy = a.y * e;
  int p = beg;
  // 8 independent row loads in flight (memory-level parallelism)
  for (; p + 8 <= end; p += 8) {
    int u0 = adj[p], u1 = adj[p + 1], u2 = adj[p + 2], u3 = adj[p + 3];
    int u4 = adj[p + 4], u5 = adj[p + 5], u6 = adj[p + 6], u7 = adj[p + 7];
    float2 b0 = hv[(size_t)u0 * 64 + lane];
    float2 b1 = hv[(size_t)u1 * 64 + lane];
    float2 b2 = hv[(size_t)u2 * 64 + lane];
    float2 b3 = hv[(size_t)u3 * 64 + lane];
    float2 b4 = hv[(size_t)u4 * 64 + lane];
    float2 b5 = hv[(size_t)u5 * 64 + lane];
    float2 b6 = hv[(size_t)u6 * 64 + lane];
    float2 b7 = hv[(size_t)u7 * 64 + lane];
    sx += ((b0.x + b1.x) + (b2.x + b3.x)) + ((b4.x + b5.x) + (b6.x + b7.x));
    sy += ((b0.y + b1.y) + (b2.y + b3.y)) + ((b4.y + b5.y) + (b6.y + b7.y));
  }
  for (; p + 2 <= end; p += 2) {
    int u0 = adj[p], u1 = adj[p + 1];
    float2 b0 = hv[(size_t)u0 * 64 + lane];
    float2 b1 = hv[(size_t)u1 * 64 + lane];
    sx += b0.x + b1.x;
    sy += b0.y + b1.y;
  }
  if (p < end) {
    int u = adj[p];
    float2 b = hv[(size_t)u * 64 + lane];
    sx += b.x; sy += b.y;
  }
  float2 o; o.x = sx; o.y = sy;
  ((float2*)z)[(size_t)wid * 64 + lane] = o;
}

// ---------------- W prep: fp32 [k][c] -> split-bf16, transposed, swizzled planes ----------------
// Granule (col, kg): 8 contiguous k of column col at granule index
// g2 = col*16 + (kg ^ (col & 7))   (16B XOR swizzle baked into the global layout)

__global__ __launch_bounds__(256) void prep_w_kernel(
    const float* w0, const float* w1, const float* w2, const float* w3, const float* w4,
    const float* w5, const float* w6, const float* w7, const float* w8,
    unsigned short* __restrict__ Wt)
{
  int m = blockIdx.x >> 3;                 // 9 matrices x 8 blocks
  int bb = blockIdx.x & 7;
  const float* ws[9] = {w0, w1, w2, w3, w4, w5, w6, w7, w8};
  const float* W = ws[m];
  unsigned short* hi = Wt + (size_t)m * 32768;
  unsigned short* lo = hi + 16384;
  int gid = bb * 256 + threadIdx.x;        // 0..2047
  int col = gid & 127;
  int kg  = gid >> 7;                      // 0..15
  short8v vh, vl;
  #pragma unroll
  for (int j = 0; j < 8; ++j) {
    float v = W[(kg * 8 + j) * H + col];
    unsigned short h, l;
    bsplit(v, h, l);
    vh[j] = (short)h;
    vl[j] = (short)l;
  }
  int g2 = col * 16 + (kg ^ (col & 7));
  *(short8v*)(hi + (size_t)g2 * 8) = vh;
  *(short8v*)(lo + (size_t)g2 * 8) = vl;
}

// ---------------- shared fragment helper ----------------

__device__ inline void load_wfrag(const unsigned short* __restrict__ Wp,
                                  int n, int lr, int kg, short8v& wh, short8v& wl) {
  int col = n * 16 + lr;
  int g2 = col * 16 + (kg ^ (col & 7));
  wh = *(const short8v*)(Wp + (size_t)g2 * 8);
  wl = *(const short8v*)(Wp + 16384 + (size_t)g2 * 8);
}

// ---------------- plain MFMA GEMM (encoder + head) ----------------

__global__ __launch_bounds__(256, 2) void gemm_mfma_kernel(
    const float* __restrict__ A, const unsigned short* __restrict__ Wt,
    float* __restrict__ out,
    const float* __restrict__ bias, const float* __restrict__ gw,
    const float* __restrict__ bb_, const float* __restrict__ bm,
    const float* __restrict__ bv, int relu, int nrows)
{
  __shared__ float4 ldsv[4096];            // 64 KB hi+lo planes
  unsigned short* lds = (unsigned short*)ldsv;
  int t = threadIdx.x;
  {
    const float4* srcv = (const float4*)Wt;
    #pragma unroll
    for (int i = 0; i < 16; ++i) ldsv[t + 256 * i] = srcv[t + 256 * i];
  }
  __syncthreads();

  int w = t >> 6, l = t & 63;
  int lr = l & 15, lk = l >> 4;
  int row0 = blockIdx.x * 128 + w * 32;

  f32x4 acc[2][8];
  #pragma unroll
  for (int m = 0; m < 2; ++m)
    #pragma unroll
    for (int n = 0; n < 8; ++n) acc[m][n] = (f32x4){0.f, 0.f, 0.f, 0.f};

  const float* Ap[2];
  #pragma unroll
  for (int m = 0; m < 2; ++m) {
    int r = row0 + m * 16 + lr;
    if (r > nrows - 1) r = nrows - 1;
    Ap[m] = A + (size_t)r * H + lk * 8;
  }

  #pragma unroll
  for (int k4 = 0; k4 < 4; ++k4) {
    short8v ah[2], al[2];
    #pragma unroll
    for (int m = 0; m < 2; ++m) {
      f32x4 a0 = *(const f32x4*)(Ap[m] + k4 * 32);
      f32x4 a1 = *(const f32x4*)(Ap[m] + k4 * 32 + 4);
      #pragma unroll
      for (int j = 0; j < 4; ++j) {
        unsigned short hh, ll;
        bsplit(a0[j], hh, ll); ah[m][j] = (short)hh; al[m][j] = (short)ll;
        bsplit(a1[j], hh, ll); ah[m][4 + j] = (short)hh; al[m][4 + j] = (short)ll;
      }
    }
    int kg = k4 * 4 + lk;
    #pragma unroll
    for (int n = 0; n < 8; ++n) {
      int col = n * 16 + lr;
      int g2 = col * 16 + (kg ^ (col & 7));
      short8v wh = *(const short8v*)(lds + (size_t)g2 * 8);
      short8v wl = *(const short8v*)(lds + 16384 + (size_t)g2 * 8);
      acc[0][n] = __builtin_amdgcn_mfma_f32_16x16x32_bf16(ah[0], wh, acc[0][n], 0, 0, 0);
      acc[1][n] = __builtin_amdgcn_mfma_f32_16x16x32_bf16(ah[1], wh, acc[1][n], 0, 0, 0);
      acc[0][n] = __builtin_amdgcn_mfma_f32_16x16x32_bf16(al[0], wh, acc[0][n], 0, 0, 0);
      acc[1][n] = __builtin_amdgcn_mfma_f32_16x16x32_bf16(al[1], wh, acc[1][n], 0, 0, 0);
      acc[0][n] = __builtin_amdgcn_mfma_f32_16x16x32_bf16(ah[0], wl, acc[0][n], 0, 0, 0);
      acc[1][n] = __builtin_amdgcn_mfma_f32_16x16x32_bf16(ah[1], wl, acc[1][n], 0, 0, 0);
      acc[0][n] = __builtin_amdgcn_mfma_f32_16x16x32_bf16(al[0], wl, acc[0][n], 0, 0, 0);
      acc[1][n] = __builtin_amdgcn_mfma_f32_16x16x32_bf16(al[1], wl, acc[1][n], 0, 0, 0);
    }
  }
  __syncthreads();

  #pragma unroll
  for (int n = 0; n < 8; ++n) {
    int c = n * 16 + lr;
    float sc = bv ? rsqrtf(bv[c] + 1e-5f) : 1.0f;
    float gg = gw ? gw[c] : 1.0f;
    float S = gg * sc;
    float T = ((bias ? bias[c] : 0.0f) - (bm ? bm[c] : 0.0f)) * S + (bb_ ? bb_[c] : 0.0f);
    #pragma unroll
    for (int m = 0; m < 2; ++m) {
      int rowb = row0 + m * 16 + lk * 4;
      #pragma unroll
      for (int r = 0; r < 4; ++r) {
        int row = rowb + r;
        if (row < nrows) {
          float vv = acc[m][n][r] * S + T;
          if (relu) vv = fmaxf(vv, 0.0f);
          out[(size_t)row * H + c] = vv;
        }
      }
    }
  }
}

// ---------------- fused per-layer MLP: relu(bn2( relu(bn1(Z@W1+b1)) @ W2 + b2 )) ----------------
// z1 stays on-chip: packed split-bf16 ((lo<<16)|hi) u32 in a 64KB XOR-swizzled LDS tile.
// W1/W2 fragments read straight from the pre-swizzled global planes (64KB each, L2-hot).
// LDS rows are wave-private (wave w owns rows [w*32, w*32+32)).

__device__ inline int zswz(int row, int col) {   // u32 index in zs[128*128]
  int s = (row ^ (row >> 3)) & 7;
  return row * 128 + (col ^ (s << 3));
}

__global__ __launch_bounds__(256, 2) void fused_mlp_kernel(
    const float* __restrict__ A, const unsigned short* __restrict__ W1,
    const unsigned short* __restrict__ W2, float* __restrict__ out,
    const float* __restrict__ b1, const float* __restrict__ g1,
    const float* __restrict__ be1, const float* __restrict__ m1, const float* __restrict__ v1,
    const float* __restrict__ b2, const float* __restrict__ g2,
    const float* __restrict__ be2, const float* __restrict__ m2, const float* __restrict__ v2,
    int nrows)
{
  __shared__ unsigned zs[128 * 128];       // 64 KB
  int t = threadIdx.x;
  int w = t >> 6, l = t & 63;
  int lr = l & 15, lk = l >> 4;
  int row0 = blockIdx.x * 128 + w * 32;

  f32x4 acc[2][8];
  #pragma unroll
  for (int m = 0; m < 2; ++m)
    #pragma unroll
    for (int n = 0; n < 8; ++n) acc[m][n] = (f32x4){0.f, 0.f, 0.f, 0.f};

  const float* Ap[2];
  #pragma unroll
  for (int m = 0; m < 2; ++m) {
    int r = row0 + m * 16 + lr;
    if (r > nrows - 1) r = nrows - 1;
    Ap[m] = A + (size_t)r * H + lk * 8;
  }

  // ---- GEMM1: acc = A @ W1 ----
  #pragma unroll
  for (int k4 = 0; k4 < 4; ++k4) {
    short8v ah[2], al[2];
    #pragma unroll
    for (int m = 0; m < 2; ++m) {
      f32x4 a0 = *(const f32x4*)(Ap[m] + k4 * 32);
      f32x4 a1 = *(const f32x4*)(Ap[m] + k4 * 32 + 4);
      #pragma unroll
      for (int j = 0; j < 4; ++j) {
        unsigned short hh, ll;
        bsplit(a0[j], hh, ll); ah[m][j] = (short)hh; al[m][j] = (short)ll;
        bsplit(a1[j], hh, ll); ah[m][4 + j] = (short)hh; al[m][4 + j] = (short)ll;
      }
    }
    int kg = k4 * 4 + lk;
    #pragma unroll
    for (int n = 0; n < 8; ++n) {
      short8v wh, wl;
      load_wfrag(W1, n, lr, kg, wh, wl);
      acc[0][n] = __builtin_amdgcn_mfma_f32_16x16x32_bf16(ah[0], wh, acc[0][n], 0, 0, 0);
      acc[1][n] = __builtin_amdgcn_mfma_f32_16x16x32_bf16(ah[1], wh, acc[1][n], 0, 0, 0);
      acc[0][n] = __builtin_amdgcn_mfma_f32_16x16x32_bf16(al[0], wh, acc[0][n], 0, 0, 0);
      acc[1][n] = __builtin_amdgcn_mfma_f32_16x16x32_bf16(al[1], wh, acc[1][n], 0, 0, 0);
      acc[0][n] = __builtin_amdgcn_mfma_f32_16x16x32_bf16(ah[0], wl, acc[0][n], 0, 0, 0);
      acc[1][n] = __builtin_amdgcn_mfma_f32_16x16x32_bf16(ah[1], wl, acc[1][n], 0, 0, 0);
      acc[0][n] = __builtin_amdgcn_mfma_f32_16x16x32_bf16(al[0], wl, acc[0][n], 0, 0, 0);
      acc[1][n] = __builtin_amdgcn_mfma_f32_16x16x32_bf16(al[1], wl, acc[1][n], 0, 0, 0);
    }
  }

  // ---- epilogue1 + pack to LDS (rows are wave-private) ----
  #pragma unroll
  for (int n = 0; n < 8; ++n) {
    int c = n * 16 + lr;
    float S = g1[c] * rsqrtf(v1[c] + 1e-5f);
    float T = (b1[c] - m1[c]) * S + be1[c];
    #pragma unroll
    for (int m = 0; m < 2; ++m) {
      int rowb = w * 32 + m * 16 + lk * 4;   // block-local row
      #pragma unroll
      for (int r = 0; r < 4; ++r) {
        float vv = fmaxf(acc[m][n][r] * S + T, 0.0f);
        unsigned short hh, ll;
        bsplit(vv, hh, ll);
        zs[zswz(rowb + r, c)] = (unsigned)hh | ((unsigned)ll << 16);
      }
    }
  }
  __syncthreads();

  // ---- GEMM2: acc = z1 @ W2 ----
  #pragma unroll
  for (int m = 0; m < 2; ++m)
    #pragma unroll
    for (int n = 0; n < 8; ++n) acc[m][n] = (f32x4){0.f, 0.f, 0.f, 0.f};

  #pragma unroll
  for (int k4 = 0; k4 < 4; ++k4) {
    short8v ah[2], al[2];
    #pragma unroll
    for (int m = 0; m < 2; ++m) {
      int rowl = w * 32 + m * 16 + lr;
      int s = (rowl ^ (rowl >> 3)) & 7;
      int base8 = (k4 * 4 + lk) ^ s;                 // 8-col granule after swizzle
      const unsigned* zp = &zs[rowl * 128 + base8 * 8];
      unsigned u0 = zp[0], u1 = zp[1], u2 = zp[2], u3 = zp[3];
      unsigned u4 = zp[4], u5 = zp[5], u6 = zp[6], u7 = zp[7];
      ah[m][0] = (short)(u0 & 0xffff); al[m][0] = (short)(u0 >> 16);
      ah[m][1] = (short)(u1 & 0xffff); al[m][1] = (short)(u1 >> 16);
      ah[m][2] = (short)(u2 & 0xffff); al[m][2] = (short)(u2 >> 16);
      ah[m][3] = (short)(u3 & 0xffff); al[m][3] = (short)(u3 >> 16);
      ah[m][4] = (short)(u4 & 0xffff); al[m][4] = (short)(u4 >> 16);
      ah[m][5] = (short)(u5 & 0xffff); al[m][5] = (short)(u5 >> 16);
      ah[m][6] = (short)(u6 & 0xffff); al[m][6] = (short)(u6 >> 16);
      ah[m][7] = (short)(u7 & 0xffff); al[m][7] = (short)(u7 >> 16);
    }
    int kg = k4 * 4 + lk;
    #pragma unroll
    for (int n = 0; n < 8; ++n) {
      short8v wh, wl;
      load_wfrag(W2, n, lr, kg, wh, wl);
      acc[0][n] = __builtin_amdgcn_mfma_f32_16x16x32_bf16(ah[0], wh, acc[0][n], 0, 0, 0);
      acc[1][n] = __builtin_amdgcn_mfma_f32_16x16x32_bf16(ah[1], wh, acc[1][n], 0, 0, 0);
      acc[0][n] = __builtin_amdgcn_mfma_f32_16x16x32_bf16(al[0], wh, acc[0][n], 0, 0, 0);
      acc[1][n] = __builtin_amdgcn_mfma_f32_16x16x32_bf16(al[1], wh, acc[1][n], 0, 0, 0);
      acc[0][n] = __builtin_amdgcn_mfma_f32_16x16x32_bf16(ah[0], wl, acc[0][n], 0, 0, 0);
      acc[1][n] = __builtin_amdgcn_mfma_f32_16x16x32_bf16(ah[1], wl, acc[1][n], 0, 0, 0);
      acc[0][n] = __builtin_amdgcn_mfma_f32_16x16x32_bf16(al[0], wl, acc[0][n], 0, 0, 0);
      acc[1][n] = __builtin_amdgcn_mfma_f32_16x16x32_bf16(al[1], wl, acc[1][n], 0, 0, 0);
    }
  }

  // ---- epilogue2 + store ----
  #pragma unroll
  for (int n = 0; n < 8; ++n) {
    int c = n * 16 + lr;
    float S = g2[c] * rsqrtf(v2[c] + 1e-5f);
    float T = (b2[c] - m2[c]) * S + be2[c];
    #pragma unroll
    for (int m = 0; m < 2; ++m) {
      int rowb = row0 + m * 16 + lk * 4;
      #pragma unroll
      for (int r = 0; r < 4; ++r) {
        int row = rowb + r;
        if (row < nrows) {
          out[(size_t)row * H + c] = fmaxf(acc[m][n][r] * S + T, 0.0f);
        }
      }
    }
  }
}

// ---------------- mean pool over sorted batch segments ----------------

__global__ __launch_bounds__(128) void pool_kernel(const float* __restrict__ h,
                                                   float* __restrict__ pooled,
                                                   const int* __restrict__ gptr) {
  int g = blockIdx.x, c = threadIdx.x;
  int beg = gptr[g], end = gptr[g + 1];
  float s = 0.0f;
  int i = beg;
  for (; i + 4 <= end; i += 4) {
    float a0 = h[(size_t)i * H + c];
    float a1 = h[(size_t)(i + 1) * H + c];
    float a2 = h[(size_t)(i + 2) * H + c];
    float a3 = h[(size_t)(i + 3) * H + c];
    s += (a0 + a1) + (a2 + a3);
  }
  for (; i < end; ++i) s += h[(size_t)i * H + c];
  float cnt = (float)(end - beg);
  pooled[(size_t)g * H + c] = s / fmaxf(cnt, 1.0f);
}

// ---------------- launch ----------------

extern "C" void kernel_launch(void* const* d_in, const int* in_sizes, int n_in,
                              void* d_out, int out_size, void* d_ws, size_t ws_size,
                              hipStream_t stream) {
  const float* x      = (const float*)d_in[0];
  const int*   ei     = (const int*)d_in[1];
  const int*   batch  = (const int*)d_in[2];
  const float* enc_W  = (const float*)d_in[3];
  const float* enc_b  = (const float*)d_in[4];
  const float* eps    = (const float*)d_in[5];
  const float* mlp1_W = (const float*)d_in[6];
  const float* mlp1_b = (const float*)d_in[7];
  const float* mlp1_g = (const float*)d_in[8];
  const float* mlp1_be= (const float*)d_in[9];
  const float* mlp1_m = (const float*)d_in[10];
  const float* mlp1_v = (const float*)d_in[11];
  const float* mlp2_W = (const float*)d_in[12];
  const float* mlp2_b = (const float*)d_in[13];
  const float* bn_g   = (const float*)d_in[14];
  const float* bn_b   = (const float*)d_in[15];
  const float* bn_m   = (const float*)d_in[16];
  const float* bn_v   = (const float*)d_in[17];
  const float* hW1    = (const float*)d_in[18];
  const float* hb1    = (const float*)d_in[19];
  const float* hg     = (const float*)d_in[20];
  const float* hbe    = (const float*)d_in[21];
  const float* hm     = (const float*)d_in[22];
  const float* hv     = (const float*)d_in[23];
  const float* hW2    = (const float*)d_in[24];
  const float* hb2    = (const float*)d_in[25];

  const int N = in_sizes[0] / H;   // 100000
  const int E = in_sizes[1] / 2;   // 1600000
  const int G = out_size / H;      // 512
  const int L = in_sizes[5];       // 3

  const int* src = ei;
  const int* dst = ei + E;

  char* p = (char*)d_ws;
  auto alloc = [&](size_t bytes) -> char* {
    char* r = p;
    p += (bytes + 255) & ~(size_t)255;
    return r;
  };
  float* bufA   = (float*)alloc((size_t)N * H * sizeof(float));
  float* bufB   = (float*)alloc((size_t)N * H * sizeof(float));
  int*   adj    = (int*)alloc((size_t)E * sizeof(int));
  int*   deg    = (int*)alloc((size_t)N * sizeof(int));
  int*   row_ptr= (int*)alloc((size_t)(N + 1) * sizeof(int));
  int*   cursor = (int*)alloc((size_t)(N + 1) * sizeof(int));
  int*   bsum   = (int*)alloc(256 * sizeof(int));
  int*   gptr   = (int*)alloc((size_t)(G + 1) * sizeof(int));
  float* pooled = (float*)alloc((size_t)G * H * sizeof(float));
  float* z1     = (float*)alloc((size_t)G * H * sizeof(float));
  unsigned short* Wt = (unsigned short*)alloc((size_t)9 * 32768 * sizeof(unsigned short));

  hipMemsetAsync(deg, 0, (size_t)N * sizeof(int), stream);

  hist_kernel<<<(E + 255) / 256, 256, 0, stream>>>(dst, deg, E);
  gptr_kernel<<<(N + 255) / 256, 256, 0, stream>>>(batch, gptr, N, G);

  int nb1 = (N + 1023) / 1024;
  scan1_kernel<<<nb1, 1024, 0, stream>>>(deg, row_ptr, bsum, N);
  scan2_kernel<<<1, 256, 0, stream>>>(bsum, nb1);
  scan3_kernel<<<nb1, 1024, 0, stream>>>(bsum, deg, row_ptr, cursor, N);

  // ranged fill: 8 passes, each pass's adj window + cursor region stay L2-hot
  const int NPASS = 8;
  for (int k = 0; k < NPASS; ++k) {
    int lo = (int)((size_t)N * k / NPASS);
    int hi = (int)((size_t)N * (k + 1) / NPASS);
    fill_adj_ranged_kernel<<<(E + 255) / 256, 256, 0, stream>>>(
        src, dst, cursor, adj, E, lo, hi);
  }

  prep_w_kernel<<<9 * 8, 256, 0, stream>>>(
      enc_W,
      mlp1_W, mlp1_W + (size_t)H * H, mlp1_W + (size_t)2 * H * H,
      mlp2_W, mlp2_W + (size_t)H * H, mlp2_W + (size_t)2 * H * H,
      hW1, hW2, Wt);

  // node encoder: h = x @ enc_W + enc_b
  gemm_mfma_kernel<<<(N + 127) / 128, 256, 0, stream>>>(
      x, Wt + 0 * 32768, bufA, enc_b, nullptr, nullptr, nullptr, nullptr, 0, N);

  float* cur = bufA;
  float* nxt = bufB;
  for (int l = 0; l < L; ++l) {
    aggregate_kernel<<<(N + 3) / 4, 256, 0, stream>>>(cur, nxt, row_ptr, adj, eps, l, N);
    fused_mlp_kernel<<<(N + 127) / 128, 256, 0, stream>>>(
        nxt, Wt + (size_t)(1 + l) * 32768, Wt + (size_t)(4 + l) * 32768, nxt,
        mlp1_b + l * H, mlp1_g + l * H, mlp1_be + l * H, mlp1_m + l * H, mlp1_v + l * H,
        mlp2_b + l * H, bn_g + l * H, bn_b + l * H, bn_m + l * H, bn_v + l * H, N);
    float* tmp = cur; cur = nxt; nxt = tmp;
  }

  pool_kernel<<<G, 128, 0, stream>>>(cur, pooled, gptr);

  gemm_mfma_kernel<<<(G + 127) / 128, 256, 0, stream>>>(
      pooled, Wt + (size_t)7 * 32768, z1, hb1, hg, hbe, hm, hv, 1, G);
  gemm_mfma_kernel<<<(G + 127) / 128, 256, 0, stream>>>(
      z1, Wt + (size_t)8 * 32768, (float*)d_out, hb2, nullptr, nullptr, nullptr, nullptr, 0, G);
}